// Round 2
// baseline (1661.834 us; speedup 1.0000x reference)
//
#include <hip/hip_runtime.h>

#define B_     16
#define C_     1024
#define NHEAD  16
#define HD     64
#define NPOS   1024   // 32*32
#define KHALF  512
#define NTILE  128
#define KC     32

#define NSPLIT1 2                    // phase1 kv-partial split
#define NCHUNK1 (NPOS / NSPLIT1)     // 512
#define NSPLIT2 4                    // phase2 n split
#define NCHUNK2 (NPOS / NSPLIT2)     // 256

// log2(10000)/256
#define THETA_SCALE 0.05190512648261504f

__device__ __forceinline__ float elu1(float v) {
    return v > 0.f ? v + 1.f : __expf(v);
}

// ---------------------------------------------------------------------------
// Phase 1: k = elu(Wk @ x_high + bk)+1 ; rope(k) ; partial kv = kr @ v^T,
// partial km = mean(k).  One block per (b, head, ns); n-chunk = 512.
// ---------------------------------------------------------------------------
__global__ void __launch_bounds__(256)
phase1_kernel(const float* __restrict__ x, const float* __restrict__ qk_w,
              const float* __restrict__ qk_b,
              float* __restrict__ kvp, float* __restrict__ kmp)
{
    __shared__ union {
        struct { float xs[KC][NTILE]; float ws[HD][KC]; } a;   // GEMM staging
        struct { float kr[HD][65];    float vs[HD][65]; } b;   // kv staging
    } u;
    __shared__ float skm[HD];

    const int tid  = threadIdx.x;
    const int tdx  = tid & 31;        // n-group
    const int tdy  = tid >> 5;        // d-group (0..7)
    const int blk  = blockIdx.x;
    const int ns   = blk % NSPLIT1;
    const int head = (blk / NSPLIT1) % NHEAD;
    const int b    = blk / (NSPLIT1 * NHEAD);

    const int wbase = C_ + head * HD;          // k-weight rows
    const float* xb = x + (size_t)b * C_ * NPOS;

    if (tid < HD) skm[tid] = 0.f;

    float kvacc[4][4];
    #pragma unroll
    for (int r = 0; r < 4; r++)
        #pragma unroll
        for (int j = 0; j < 4; j++) kvacc[r][j] = 0.f;

    // per-thread rope frequencies (pair index fixed per r)
    float tf[8];
    {
        const int plbase = head * 32 + (tdy >> 1);
        #pragma unroll
        for (int r = 0; r < 8; r++)
            tf[r] = exp2f(-(float)((plbase + 4 * r) & 255) * THETA_SCALE);
    }
    const bool htype = (head < 8);

    const int d0 = (tid >> 4) * 4;   // kv-GEMM map
    const int e0 = (tid & 15) * 4;

    for (int t = 0; t < NCHUNK1 / NTILE; ++t) {
        const int nbase = ns * NCHUNK1 + t * NTILE;
        float acc[8][4];
        #pragma unroll
        for (int r = 0; r < 8; r++)
            #pragma unroll
            for (int j = 0; j < 4; j++) acc[r][j] = 0.f;

        // ---- main GEMM: k_pre[64][128] = Wk_slice @ x_high ----
        for (int k0 = 0; k0 < KHALF; k0 += KC) {
            __syncthreads();
            #pragma unroll
            for (int i = 0; i < 4; i++) {
                int idx = tid + 256 * i;
                int row = idx >> 5, col = (idx & 31) * 4;
                *(float4*)&u.a.xs[row][col] =
                    *(const float4*)&xb[(size_t)(KHALF + k0 + row) * NPOS + nbase + col];
            }
            #pragma unroll
            for (int i = 0; i < 2; i++) {
                int idx = tid + 256 * i;
                int row = idx >> 3, col = (idx & 7) * 4;
                *(float4*)&u.a.ws[row][col] =
                    *(const float4*)&qk_w[(size_t)(wbase + row) * KHALF + k0 + col];
            }
            __syncthreads();
            #pragma unroll
            for (int kk = 0; kk < KC; ++kk) {
                float4 xv = *(const float4*)&u.a.xs[kk][tdx * 4];
                float wv[8];
                #pragma unroll
                for (int r = 0; r < 8; r++) wv[r] = u.a.ws[tdy + 8 * r][kk];
                #pragma unroll
                for (int r = 0; r < 8; r++) {
                    acc[r][0] += wv[r] * xv.x; acc[r][1] += wv[r] * xv.y;
                    acc[r][2] += wv[r] * xv.z; acc[r][3] += wv[r] * xv.w;
                }
            }
        }

        // ---- bias + elu + 1 ----
        #pragma unroll
        for (int r = 0; r < 8; r++) {
            float bias = qk_b[C_ + head * HD + tdy + 8 * r];
            #pragma unroll
            for (int j = 0; j < 4; j++) acc[r][j] = elu1(acc[r][j] + bias);
        }

        // ---- km partial (sum over this block's n) ----
        #pragma unroll
        for (int r = 0; r < 8; r++) {
            float s = acc[r][0] + acc[r][1] + acc[r][2] + acc[r][3];
            s += __shfl_xor(s, 1);  s += __shfl_xor(s, 2);  s += __shfl_xor(s, 4);
            s += __shfl_xor(s, 8);  s += __shfl_xor(s, 16);
            if (tdx == 0) skm[tdy + 8 * r] += s;   // unique writer per d
        }

        // ---- rope: kr = rotate(k) (partner channel via lane^32) ----
        float krv[8][4];
        const int nb0  = nbase + tdx * 4;
        const int hpos = nb0 >> 5;
        #pragma unroll
        for (int r = 0; r < 8; r++) {
            #pragma unroll
            for (int j = 0; j < 4; j++) {
                int pos = htype ? hpos : ((nb0 + j) & 31);
                float ang = (float)pos * tf[r];
                float sn, cs;
                __sincosf(ang, &sn, &cs);
                float partner = __shfl_xor(acc[r][j], 32);
                krv[r][j] = (tdy & 1) ? (sn * partner + cs * acc[r][j])
                                      : (cs * acc[r][j] - sn * partner);
            }
        }

        // ---- kv accumulation over two 64-col halves ----
        #pragma unroll
        for (int hh = 0; hh < 2; ++hh) {
            __syncthreads();   // protect union + previous half reads
            if ((tdx >> 4) == hh) {
                int ncol = (tdx & 15) * 4;
                #pragma unroll
                for (int r = 0; r < 8; r++)
                    #pragma unroll
                    for (int j = 0; j < 4; j++)
                        u.b.kr[tdy + 8 * r][ncol + j] = krv[r][j];
            }
            #pragma unroll
            for (int i = 0; i < 4; i++) {
                int idx = tid + 256 * i;
                int row = idx >> 4, col = (idx & 15) * 4;
                float4 vv = *(const float4*)&xb[(size_t)(head * HD + row) * NPOS
                                                + nbase + hh * 64 + col];
                u.b.vs[row][col + 0] = vv.x; u.b.vs[row][col + 1] = vv.y;
                u.b.vs[row][col + 2] = vv.z; u.b.vs[row][col + 3] = vv.w;
            }
            __syncthreads();
            #pragma unroll 4
            for (int n = 0; n < 64; ++n) {
                float rk[4], vv[4];
                #pragma unroll
                for (int r = 0; r < 4; r++) rk[r] = u.b.kr[d0 + r][n];
                #pragma unroll
                for (int j = 0; j < 4; j++) vv[j] = u.b.vs[e0 + j][n];
                #pragma unroll
                for (int r = 0; r < 4; r++)
                    #pragma unroll
                    for (int j = 0; j < 4; j++)
                        kvacc[r][j] += rk[r] * vv[j];
            }
        }
    }

    __syncthreads();
    const int bh = b * NHEAD + head;
    float* kvdst = kvp + ((size_t)ns * 256 + bh) * 4096;
    const float s2 = 1.f / 1024.f;   // s*s with n=1024
    #pragma unroll
    for (int r = 0; r < 4; r++) {
        float4 o = make_float4(kvacc[r][0] * s2, kvacc[r][1] * s2,
                               kvacc[r][2] * s2, kvacc[r][3] * s2);
        *(float4*)&kvdst[(d0 + r) * 64 + e0] = o;
    }
    if (tid < HD)
        kmp[((size_t)ns * 256 + bh) * 64 + tid] = skm[tid] * (1.f / 1024.f);
}

// ---------------------------------------------------------------------------
// Phase 2: q = elu(Wq @ x_low + bq)+1 ; z = 1/(q.km+eps) ; rope(q) ;
// out = (qr^T kv) * z + lepe(x).  One block per (b, head, ns2).
// ---------------------------------------------------------------------------
__global__ void __launch_bounds__(256)
phase2_kernel(const float* __restrict__ x, const float* __restrict__ qk_w,
              const float* __restrict__ qk_b,
              const float* __restrict__ lepe_w, const float* __restrict__ lepe_b,
              const float* __restrict__ kvp, const float* __restrict__ kmp,
              float* __restrict__ out)
{
    __shared__ union {
        struct { float xs[KC][NTILE]; float ws[HD][KC]; } a;
        float qr[HD][132];
    } u;
    __shared__ float kvs[HD][65];
    __shared__ float kms[HD];
    __shared__ float sz[NTILE];

    const int tid  = threadIdx.x;
    const int tdx  = tid & 31;
    const int tdy  = tid >> 5;
    const int blk  = blockIdx.x;
    const int ns   = blk % NSPLIT2;
    const int head = (blk / NSPLIT2) % NHEAD;
    const int b    = blk / (NSPLIT2 * NHEAD);

    const int wbase = head * HD;               // q-weight rows
    const float* xb = x + (size_t)b * C_ * NPOS;
    const int bh = b * NHEAD + head;

    // ---- load kv (sum of NSPLIT1 partials) and km into LDS ----
    #pragma unroll
    for (int i = 0; i < 16; i++) {
        int idx = tid + 256 * i;
        float v = 0.f;
        #pragma unroll
        for (int s = 0; s < NSPLIT1; s++)
            v += kvp[((size_t)s * 256 + bh) * 4096 + idx];
        kvs[idx >> 6][idx & 63] = v;
    }
    if (tid < HD) {
        float v = 0.f;
        #pragma unroll
        for (int s = 0; s < NSPLIT1; s++)
            v += kmp[((size_t)s * 256 + bh) * 64 + tid];
        kms[tid] = v;
    }
    // first __syncthreads inside the K-loop publishes these

    float tf[8];
    {
        const int plbase = head * 32 + (tdy >> 1);
        #pragma unroll
        for (int r = 0; r < 8; r++)
            tf[r] = exp2f(-(float)((plbase + 4 * r) & 255) * THETA_SCALE);
    }
    const bool htype = (head < 8);

    for (int t = 0; t < NCHUNK2 / NTILE; ++t) {
        const int nbase = ns * NCHUNK2 + t * NTILE;
        float acc[8][4];
        #pragma unroll
        for (int r = 0; r < 8; r++)
            #pragma unroll
            for (int j = 0; j < 4; j++) acc[r][j] = 0.f;

        // ---- main GEMM: q_pre[64][128] = Wq_slice @ x_low ----
        for (int k0 = 0; k0 < KHALF; k0 += KC) {
            __syncthreads();
            #pragma unroll
            for (int i = 0; i < 4; i++) {
                int idx = tid + 256 * i;
                int row = idx >> 5, col = (idx & 31) * 4;
                *(float4*)&u.a.xs[row][col] =
                    *(const float4*)&xb[(size_t)(k0 + row) * NPOS + nbase + col];
            }
            #pragma unroll
            for (int i = 0; i < 2; i++) {
                int idx = tid + 256 * i;
                int row = idx >> 3, col = (idx & 7) * 4;
                *(float4*)&u.a.ws[row][col] =
                    *(const float4*)&qk_w[(size_t)(wbase + row) * KHALF + k0 + col];
            }
            __syncthreads();
            #pragma unroll
            for (int kk = 0; kk < KC; ++kk) {
                float4 xv = *(const float4*)&u.a.xs[kk][tdx * 4];
                float wv[8];
                #pragma unroll
                for (int r = 0; r < 8; r++) wv[r] = u.a.ws[tdy + 8 * r][kk];
                #pragma unroll
                for (int r = 0; r < 8; r++) {
                    acc[r][0] += wv[r] * xv.x; acc[r][1] += wv[r] * xv.y;
                    acc[r][2] += wv[r] * xv.z; acc[r][3] += wv[r] * xv.w;
                }
            }
        }

        #pragma unroll
        for (int r = 0; r < 8; r++) {
            float bias = qk_b[head * HD + tdy + 8 * r];
            #pragma unroll
            for (int j = 0; j < 4; j++) acc[r][j] = elu1(acc[r][j] + bias);
        }

        __syncthreads();               // GEMM staging reads done; kvs/kms ready
        if (tid < NTILE) sz[tid] = 0.f;
        __syncthreads();

        // ---- z partials + rope + stage qr into LDS ----
        const int nb0  = nbase + tdx * 4;
        const int hpos = nb0 >> 5;
        float part[4] = {0.f, 0.f, 0.f, 0.f};
        #pragma unroll
        for (int r = 0; r < 8; r++) {
            float km = kms[tdy + 8 * r];
            float4 q4;
            float qr_[4];
            #pragma unroll
            for (int j = 0; j < 4; j++) {
                part[j] += acc[r][j] * km;
                int pos = htype ? hpos : ((nb0 + j) & 31);
                float ang = (float)pos * tf[r];
                float sn, cs;
                __sincosf(ang, &sn, &cs);
                float partner = __shfl_xor(acc[r][j], 32);
                qr_[j] = (tdy & 1) ? (sn * partner + cs * acc[r][j])
                                   : (cs * acc[r][j] - sn * partner);
            }
            q4.x = qr_[0]; q4.y = qr_[1]; q4.z = qr_[2]; q4.w = qr_[3];
            *(float4*)&u.qr[tdy + 8 * r][tdx * 4] = q4;
        }
        #pragma unroll
        for (int j = 0; j < 4; j++) atomicAdd(&sz[tdx * 4 + j], part[j]);
        __syncthreads();

        // ---- out GEMM: out[e][n] = sum_d qr[d][n] * kv[d][e] ----
        float zq[4];
        #pragma unroll
        for (int j = 0; j < 4; j++) zq[j] = 1.f / (sz[tdx * 4 + j] + 1e-6f);

        float acc2[8][4];
        #pragma unroll
        for (int r = 0; r < 8; r++)
            #pragma unroll
            for (int j = 0; j < 4; j++) acc2[r][j] = 0.f;

        for (int d = 0; d < HD; ++d) {
            float4 q4 = *(const float4*)&u.qr[d][tdx * 4];
            #pragma unroll
            for (int r = 0; r < 8; r++) {
                float kvv = kvs[d][tdy + 8 * r];
                acc2[r][0] += kvv * q4.x; acc2[r][1] += kvv * q4.y;
                acc2[r][2] += kvv * q4.z; acc2[r][3] += kvv * q4.w;
            }
        }

        // ---- lepe (depthwise 3x3, SAME) + final store ----
        const int n0 = nbase + tdx * 4;
        const int h  = n0 >> 5;
        const int w0 = n0 & 31;
        #pragma unroll
        for (int r = 0; r < 8; r++) {
            const int c = head * HD + tdy + 8 * r;
            const float* lw = lepe_w + c * 9;
            float lwv[9];
            #pragma unroll
            for (int m = 0; m < 9; m++) lwv[m] = lw[m];
            float lb = lepe_b[c];
            float lac[4] = {lb, lb, lb, lb};
            const float* xc = xb + (size_t)c * NPOS;
            #pragma unroll
            for (int kh = 0; kh < 3; kh++) {
                int hh = h + kh - 1;
                if ((unsigned)hh < 32u) {
                    float tbuf[6];
                    #pragma unroll
                    for (int m = 0; m < 6; m++) {
                        int ww = w0 - 1 + m;
                        tbuf[m] = ((unsigned)ww < 32u) ? xc[hh * 32 + ww] : 0.f;
                    }
                    #pragma unroll
                    for (int j = 0; j < 4; j++)
                        #pragma unroll
                        for (int kw = 0; kw < 3; kw++)
                            lac[j] += tbuf[j + kw] * lwv[kh * 3 + kw];
                }
            }
            float4 o;
            o.x = acc2[r][0] * zq[0] + lac[0];
            o.y = acc2[r][1] * zq[1] + lac[1];
            o.z = acc2[r][2] * zq[2] + lac[2];
            o.w = acc2[r][3] * zq[3] + lac[3];
            *(float4*)&out[(size_t)(b * C_ + c) * NPOS + n0] = o;
        }
    }
}

// ---------------------------------------------------------------------------
// Fused fallback (ZERO workspace): one block per (b, head).  Stage A = full
// k/kv/km over all n into registers+LDS; Stage B = q/out/lepe per tile.
// ---------------------------------------------------------------------------
__global__ void __launch_bounds__(256)
fused_kernel(const float* __restrict__ x, const float* __restrict__ qk_w,
             const float* __restrict__ qk_b,
             const float* __restrict__ lepe_w, const float* __restrict__ lepe_b,
             float* __restrict__ out)
{
    __shared__ union {
        struct { float xs[KC][NTILE]; float ws[HD][KC]; } a;
        struct { float kr[HD][65];    float vs[HD][65]; } b;
        float qr[HD][132];
    } u;
    __shared__ float kvs[HD][65];
    __shared__ float kms[HD];
    __shared__ float sz[NTILE];

    const int tid  = threadIdx.x;
    const int tdx  = tid & 31;
    const int tdy  = tid >> 5;
    const int head = blockIdx.x % NHEAD;
    const int b    = blockIdx.x / NHEAD;

    const float* xb = x + (size_t)b * C_ * NPOS;

    if (tid < HD) kms[tid] = 0.f;

    float kvacc[4][4];
    #pragma unroll
    for (int r = 0; r < 4; r++)
        #pragma unroll
        for (int j = 0; j < 4; j++) kvacc[r][j] = 0.f;

    float tf[8];
    {
        const int plbase = head * 32 + (tdy >> 1);
        #pragma unroll
        for (int r = 0; r < 8; r++)
            tf[r] = exp2f(-(float)((plbase + 4 * r) & 255) * THETA_SCALE);
    }
    const bool htype = (head < 8);

    const int d0 = (tid >> 4) * 4;
    const int e0 = (tid & 15) * 4;

    // ================= Stage A: k phase over all 8 tiles =================
    for (int t = 0; t < NPOS / NTILE; ++t) {
        const int nbase = t * NTILE;
        float acc[8][4];
        #pragma unroll
        for (int r = 0; r < 8; r++)
            #pragma unroll
            for (int j = 0; j < 4; j++) acc[r][j] = 0.f;

        for (int k0 = 0; k0 < KHALF; k0 += KC) {
            __syncthreads();
            #pragma unroll
            for (int i = 0; i < 4; i++) {
                int idx = tid + 256 * i;
                int row = idx >> 5, col = (idx & 31) * 4;
                *(float4*)&u.a.xs[row][col] =
                    *(const float4*)&xb[(size_t)(KHALF + k0 + row) * NPOS + nbase + col];
            }
            #pragma unroll
            for (int i = 0; i < 2; i++) {
                int idx = tid + 256 * i;
                int row = idx >> 3, col = (idx & 7) * 4;
                *(float4*)&u.a.ws[row][col] =
                    *(const float4*)&qk_w[(size_t)(C_ + head * HD + row) * KHALF + k0 + col];
            }
            __syncthreads();
            #pragma unroll
            for (int kk = 0; kk < KC; ++kk) {
                float4 xv = *(const float4*)&u.a.xs[kk][tdx * 4];
                float wv[8];
                #pragma unroll
                for (int r = 0; r < 8; r++) wv[r] = u.a.ws[tdy + 8 * r][kk];
                #pragma unroll
                for (int r = 0; r < 8; r++) {
                    acc[r][0] += wv[r] * xv.x; acc[r][1] += wv[r] * xv.y;
                    acc[r][2] += wv[r] * xv.z; acc[r][3] += wv[r] * xv.w;
                }
            }
        }

        #pragma unroll
        for (int r = 0; r < 8; r++) {
            float bias = qk_b[C_ + head * HD + tdy + 8 * r];
            #pragma unroll
            for (int j = 0; j < 4; j++) acc[r][j] = elu1(acc[r][j] + bias);
        }

        #pragma unroll
        for (int r = 0; r < 8; r++) {
            float s = acc[r][0] + acc[r][1] + acc[r][2] + acc[r][3];
            s += __shfl_xor(s, 1);  s += __shfl_xor(s, 2);  s += __shfl_xor(s, 4);
            s += __shfl_xor(s, 8);  s += __shfl_xor(s, 16);
            if (tdx == 0) kms[tdy + 8 * r] += s;
        }

        float krv[8][4];
        const int nb0  = nbase + tdx * 4;
        const int hpos = nb0 >> 5;
        #pragma unroll
        for (int r = 0; r < 8; r++) {
            #pragma unroll
            for (int j = 0; j < 4; j++) {
                int pos = htype ? hpos : ((nb0 + j) & 31);
                float ang = (float)pos * tf[r];
                float sn, cs;
                __sincosf(ang, &sn, &cs);
                float partner = __shfl_xor(acc[r][j], 32);
                krv[r][j] = (tdy & 1) ? (sn * partner + cs * acc[r][j])
                                      : (cs * acc[r][j] - sn * partner);
            }
        }

        #pragma unroll
        for (int hh = 0; hh < 2; ++hh) {
            __syncthreads();
            if ((tdx >> 4) == hh) {
                int ncol = (tdx & 15) * 4;
                #pragma unroll
                for (int r = 0; r < 8; r++)
                    #pragma unroll
                    for (int j = 0; j < 4; j++)
                        u.b.kr[tdy + 8 * r][ncol + j] = krv[r][j];
            }
            #pragma unroll
            for (int i = 0; i < 4; i++) {
                int idx = tid + 256 * i;
                int row = idx >> 4, col = (idx & 15) * 4;
                float4 vv = *(const float4*)&xb[(size_t)(head * HD + row) * NPOS
                                                + nbase + hh * 64 + col];
                u.b.vs[row][col + 0] = vv.x; u.b.vs[row][col + 1] = vv.y;
                u.b.vs[row][col + 2] = vv.z; u.b.vs[row][col + 3] = vv.w;
            }
            __syncthreads();
            #pragma unroll 4
            for (int n = 0; n < 64; ++n) {
                float rk[4], vv[4];
                #pragma unroll
                for (int r = 0; r < 4; r++) rk[r] = u.b.kr[d0 + r][n];
                #pragma unroll
                for (int j = 0; j < 4; j++) vv[j] = u.b.vs[e0 + j][n];
                #pragma unroll
                for (int r = 0; r < 4; r++)
                    #pragma unroll
                    for (int j = 0; j < 4; j++)
                        kvacc[r][j] += rk[r] * vv[j];
            }
        }
    }

    // ============== boundary: kvacc -> LDS kvs, scale km ==============
    __syncthreads();
    {
        const float s2 = 1.f / 1024.f;
        #pragma unroll
        for (int r = 0; r < 4; r++)
            #pragma unroll
            for (int j = 0; j < 4; j++)
                kvs[d0 + r][e0 + j] = kvacc[r][j] * s2;
        if (tid < HD) kms[tid] *= (1.f / 1024.f);
    }
    __syncthreads();

    // ================= Stage B: q phase over all 8 tiles =================
    for (int t = 0; t < NPOS / NTILE; ++t) {
        const int nbase = t * NTILE;
        float acc[8][4];
        #pragma unroll
        for (int r = 0; r < 8; r++)
            #pragma unroll
            for (int j = 0; j < 4; j++) acc[r][j] = 0.f;

        for (int k0 = 0; k0 < KHALF; k0 += KC) {
            __syncthreads();
            #pragma unroll
            for (int i = 0; i < 4; i++) {
                int idx = tid + 256 * i;
                int row = idx >> 5, col = (idx & 31) * 4;
                *(float4*)&u.a.xs[row][col] =
                    *(const float4*)&xb[(size_t)(k0 + row) * NPOS + nbase + col];
            }
            #pragma unroll
            for (int i = 0; i < 2; i++) {
                int idx = tid + 256 * i;
                int row = idx >> 3, col = (idx & 7) * 4;
                *(float4*)&u.a.ws[row][col] =
                    *(const float4*)&qk_w[(size_t)(head * HD + row) * KHALF + k0 + col];
            }
            __syncthreads();
            #pragma unroll
            for (int kk = 0; kk < KC; ++kk) {
                float4 xv = *(const float4*)&u.a.xs[kk][tdx * 4];
                float wv[8];
                #pragma unroll
                for (int r = 0; r < 8; r++) wv[r] = u.a.ws[tdy + 8 * r][kk];
                #pragma unroll
                for (int r = 0; r < 8; r++) {
                    acc[r][0] += wv[r] * xv.x; acc[r][1] += wv[r] * xv.y;
                    acc[r][2] += wv[r] * xv.z; acc[r][3] += wv[r] * xv.w;
                }
            }
        }

        #pragma unroll
        for (int r = 0; r < 8; r++) {
            float bias = qk_b[head * HD + tdy + 8 * r];
            #pragma unroll
            for (int j = 0; j < 4; j++) acc[r][j] = elu1(acc[r][j] + bias);
        }

        __syncthreads();
        if (tid < NTILE) sz[tid] = 0.f;
        __syncthreads();

        const int nb0  = nbase + tdx * 4;
        const int hpos = nb0 >> 5;
        float part[4] = {0.f, 0.f, 0.f, 0.f};
        #pragma unroll
        for (int r = 0; r < 8; r++) {
            float km = kms[tdy + 8 * r];
            float4 q4;
            float qr_[4];
            #pragma unroll
            for (int j = 0; j < 4; j++) {
                part[j] += acc[r][j] * km;
                int pos = htype ? hpos : ((nb0 + j) & 31);
                float ang = (float)pos * tf[r];
                float sn, cs;
                __sincosf(ang, &sn, &cs);
                float partner = __shfl_xor(acc[r][j], 32);
                qr_[j] = (tdy & 1) ? (sn * partner + cs * acc[r][j])
                                   : (cs * acc[r][j] - sn * partner);
            }
            q4.x = qr_[0]; q4.y = qr_[1]; q4.z = qr_[2]; q4.w = qr_[3];
            *(float4*)&u.qr[tdy + 8 * r][tdx * 4] = q4;
        }
        #pragma unroll
        for (int j = 0; j < 4; j++) atomicAdd(&sz[tdx * 4 + j], part[j]);
        __syncthreads();

        float zq[4];
        #pragma unroll
        for (int j = 0; j < 4; j++) zq[j] = 1.f / (sz[tdx * 4 + j] + 1e-6f);

        float acc2[8][4];
        #pragma unroll
        for (int r = 0; r < 8; r++)
            #pragma unroll
            for (int j = 0; j < 4; j++) acc2[r][j] = 0.f;

        for (int d = 0; d < HD; ++d) {
            float4 q4 = *(const float4*)&u.qr[d][tdx * 4];
            #pragma unroll
            for (int r = 0; r < 8; r++) {
                float kvv = kvs[d][tdy + 8 * r];
                acc2[r][0] += kvv * q4.x; acc2[r][1] += kvv * q4.y;
                acc2[r][2] += kvv * q4.z; acc2[r][3] += kvv * q4.w;
            }
        }

        const int n0 = nbase + tdx * 4;
        const int h  = n0 >> 5;
        const int w0 = n0 & 31;
        #pragma unroll
        for (int r = 0; r < 8; r++) {
            const int c = head * HD + tdy + 8 * r;
            const float* lw = lepe_w + c * 9;
            float lwv[9];
            #pragma unroll
            for (int m = 0; m < 9; m++) lwv[m] = lw[m];
            float lb = lepe_b[c];
            float lac[4] = {lb, lb, lb, lb};
            const float* xc = xb + (size_t)c * NPOS;
            #pragma unroll
            for (int kh = 0; kh < 3; kh++) {
                int hh = h + kh - 1;
                if ((unsigned)hh < 32u) {
                    float tbuf[6];
                    #pragma unroll
                    for (int m = 0; m < 6; m++) {
                        int ww = w0 - 1 + m;
                        tbuf[m] = ((unsigned)ww < 32u) ? xc[hh * 32 + ww] : 0.f;
                    }
                    #pragma unroll
                    for (int j = 0; j < 4; j++)
                        #pragma unroll
                        for (int kw = 0; kw < 3; kw++)
                            lac[j] += tbuf[j + kw] * lwv[kh * 3 + kw];
                }
            }
            float4 o;
            o.x = acc2[r][0] * zq[0] + lac[0];
            o.y = acc2[r][1] * zq[1] + lac[1];
            o.z = acc2[r][2] * zq[2] + lac[2];
            o.w = acc2[r][3] * zq[3] + lac[3];
            *(float4*)&out[(size_t)(b * C_ + c) * NPOS + n0] = o;
        }
    }
}

// ---------------------------------------------------------------------------
extern "C" void kernel_launch(void* const* d_in, const int* in_sizes, int n_in,
                              void* d_out, int out_size, void* d_ws, size_t ws_size,
                              hipStream_t stream)
{
    const float* x      = (const float*)d_in[0];
    const float* qk_w   = (const float*)d_in[1];
    const float* qk_b   = (const float*)d_in[2];
    const float* lepe_w = (const float*)d_in[3];
    const float* lepe_b = (const float*)d_in[4];
    float* out = (float*)d_out;

    // workspace need: NSPLIT1 * 256 * (4096 + 64) floats = 8,519,680 bytes
    const size_t need = (size_t)NSPLIT1 * 256 * (4096 + 64) * sizeof(float);

    if (ws_size >= need) {
        float* kvp = (float*)d_ws;
        float* kmp = kvp + (size_t)NSPLIT1 * 256 * 4096;
        phase1_kernel<<<dim3(NSPLIT1 * B_ * NHEAD), dim3(256), 0, stream>>>(
            x, qk_w, qk_b, kvp, kmp);
        phase2_kernel<<<dim3(NSPLIT2 * B_ * NHEAD), dim3(256), 0, stream>>>(
            x, qk_w, qk_b, lepe_w, lepe_b, kvp, kmp, out);
    } else {
        fused_kernel<<<dim3(B_ * NHEAD), dim3(256), 0, stream>>>(
            x, qk_w, qk_b, lepe_w, lepe_b, out);
    }
}

// Round 3
// 697.168 us; speedup vs baseline: 2.3837x; 2.3837x over previous
//
#include <hip/hip_runtime.h>

#define B_      16
#define NHEAD   16
#define HD      64
#define NPOS    1024   // 32*32
#define KHALF   512
#define NTILE   128
#define NSPLIT2 4

// log2(10000)/256
#define THETA_SCALE 0.05190512648261504f

typedef __attribute__((ext_vector_type(8))) short bf16x8;   // 8 bf16 = 4 VGPR
typedef __attribute__((ext_vector_type(4))) float f32x4;    // MFMA C/D

__device__ __forceinline__ float elu1(float v) {
    return v > 0.f ? v + 1.f : __expf(v);
}
__device__ __forceinline__ ushort f2bf(float f) {   // fp32 -> bf16 RNE
    unsigned u = __float_as_uint(f);
    return (ushort)((u + 0x7fffu + ((u >> 16) & 1u)) >> 16);
}

// ---------------------------------------------------------------------------
// Phase 1: k = elu(Wk @ x_high + bk)+1 ; rope(k) ; partial kv = kr @ v^T (MFMA),
// partial km.  One block per (b, head, ns).
// ---------------------------------------------------------------------------
__global__ void __launch_bounds__(256)
phase1_kernel(const float* __restrict__ x, const float* __restrict__ qk_w,
              const float* __restrict__ qk_b,
              float* __restrict__ kvp, float* __restrict__ kmp, int ns1)
{
    __shared__ union {
        struct { ushort ws[64][40];  ushort xs[128][40]; } a;   // GEMM staging (bf16)
        struct { ushort kr[64][136]; ushort vs[64][136]; } b;   // kv staging (bf16)
    } u;
    __shared__ float skm[HD];
    __shared__ float bias_s[HD];

    const int tid = threadIdx.x;
    const int w   = tid >> 6;          // wave 0..3
    const int g   = (tid >> 4) & 3;    // 16-lane group within wave
    const int lm  = tid & 15;

    const int ns   = blockIdx.x % ns1;
    const int head = (blockIdx.x / ns1) % NHEAD;
    const int b    = blockIdx.x / (ns1 * NHEAD);

    const float* xb = x + (size_t)b * 1024 * NPOS;
    const int wrow  = 1024 + head * HD;     // k-weight rows in qk_w

    if (tid < HD) { skm[tid] = 0.f; bias_s[tid] = qk_b[1024 + head * HD + tid]; }

    // rope freqs per (db, pair): theta index = (head*32 + d/2) & 255, d = 16db+4g+2rp(+1)
    float tf[4][2];
    #pragma unroll
    for (int db = 0; db < 4; db++)
        #pragma unroll
        for (int rp = 0; rp < 2; rp++)
            tf[db][rp] = exp2f(-(float)((head * 32 + 8 * db + 2 * g + rp) & 255) * THETA_SCALE);
    const bool htype = (head < 8);

    f32x4 kvf[4] = {{0,0,0,0},{0,0,0,0},{0,0,0,0},{0,0,0,0}};  // d-block w, eb 0..3

    const int nchunk = NPOS / ns1;
    const int ntiles = nchunk / NTILE;
    const int xn = tid & 127, xk = tid >> 7;   // X staging: column xn, k-half xk

    for (int t = 0; t < ntiles; ++t) {
        const int nbase = ns * nchunk + t * NTILE;

        f32x4 acc[4][2];
        #pragma unroll
        for (int db = 0; db < 4; db++)
            #pragma unroll
            for (int nb = 0; nb < 2; nb++) acc[db][nb] = (f32x4){0,0,0,0};

        // ---- k_pre[64][128] = Wk @ x_high via MFMA ----
        for (int k0 = 0; k0 < KHALF; k0 += 32) {
            __syncthreads();
            #pragma unroll
            for (int i = 0; i < 2; i++) {             // W tile 64x32
                int idx = tid + 256 * i;
                int d = idx >> 3, kq = (idx & 7) * 4;
                float4 v4 = *(const float4*)&qk_w[(size_t)(wrow + d) * KHALF + k0 + kq];
                ushort4 p; p.x = f2bf(v4.x); p.y = f2bf(v4.y);
                p.z = f2bf(v4.z); p.w = f2bf(v4.w);
                *(ushort4*)&u.a.ws[d][kq] = p;
            }
            {                                          // X tile 32x128 -> [n][k]
                const float* xcol = &xb[(size_t)(KHALF + k0 + 16 * xk) * NPOS + nbase + xn];
                #pragma unroll
                for (int q8 = 0; q8 < 4; q8++) {
                    ushort4 p;
                    p.x = f2bf(xcol[(size_t)(4 * q8 + 0) * NPOS]);
                    p.y = f2bf(xcol[(size_t)(4 * q8 + 1) * NPOS]);
                    p.z = f2bf(xcol[(size_t)(4 * q8 + 2) * NPOS]);
                    p.w = f2bf(xcol[(size_t)(4 * q8 + 3) * NPOS]);
                    *(ushort4*)&u.a.xs[xn][16 * xk + 4 * q8] = p;
                }
            }
            __syncthreads();
            bf16x8 af[4], bfr[2];
            #pragma unroll
            for (int db = 0; db < 4; db++) af[db] = *(bf16x8*)&u.a.ws[16 * db + lm][8 * g];
            #pragma unroll
            for (int nb = 0; nb < 2; nb++) bfr[nb] = *(bf16x8*)&u.a.xs[32 * w + 16 * nb + lm][8 * g];
            #pragma unroll
            for (int db = 0; db < 4; db++)
                #pragma unroll
                for (int nb = 0; nb < 2; nb++)
                    acc[db][nb] = __builtin_amdgcn_mfma_f32_16x16x32_bf16(
                        af[db], bfr[nb], acc[db][nb], 0, 0, 0);
        }

        // ---- bias + elu + 1 (D-layout: d = 16db+4g+r, n = 32w+16nb+lm) ----
        float kqv[4][2][4];
        #pragma unroll
        for (int db = 0; db < 4; db++)
            #pragma unroll
            for (int nb = 0; nb < 2; nb++)
                #pragma unroll
                for (int r = 0; r < 4; r++)
                    kqv[db][nb][r] = elu1(acc[db][nb][r] + bias_s[16 * db + 4 * g + r]);

        // ---- km partial ----
        #pragma unroll
        for (int db = 0; db < 4; db++)
            #pragma unroll
            for (int r = 0; r < 4; r++) {
                float s = kqv[db][0][r] + kqv[db][1][r];
                s += __shfl_xor(s, 1); s += __shfl_xor(s, 2);
                s += __shfl_xor(s, 4); s += __shfl_xor(s, 8);
                if (lm == 0) atomicAdd(&skm[16 * db + 4 * g + r], s);
            }

        // ---- rope (pairs are adjacent r within lane) ----
        float krv[4][2][4];
        #pragma unroll
        for (int db = 0; db < 4; db++)
            #pragma unroll
            for (int nb = 0; nb < 2; nb++) {
                int n = nbase + 32 * w + 16 * nb + lm;
                float pos_h = (float)(n >> 5), pos_w = (float)(n & 31);
                float pos = htype ? pos_h : pos_w;
                #pragma unroll
                for (int rp = 0; rp < 2; rp++) {
                    float ang = pos * tf[db][rp];
                    float sn, cs; __sincosf(ang, &sn, &cs);
                    float xr = kqv[db][nb][2 * rp], xi = kqv[db][nb][2 * rp + 1];
                    krv[db][nb][2 * rp]     = cs * xr - sn * xi;
                    krv[db][nb][2 * rp + 1] = sn * xr + cs * xi;
                }
            }

        // ---- stage kr [d][n] + v [e][n] (bf16), then kv MFMA ----
        __syncthreads();
        #pragma unroll
        for (int db = 0; db < 4; db++)
            #pragma unroll
            for (int nb = 0; nb < 2; nb++)
                #pragma unroll
                for (int r = 0; r < 4; r++)
                    u.b.kr[16 * db + 4 * g + r][32 * w + 16 * nb + lm] = f2bf(krv[db][nb][r]);
        #pragma unroll
        for (int i = 0; i < 8; i++) {
            int idx = tid + 256 * i;
            int e = idx >> 5, n0 = (idx & 31) * 4;
            float4 v4 = *(const float4*)&xb[(size_t)(head * HD + e) * NPOS + nbase + n0];
            ushort4 p; p.x = f2bf(v4.x); p.y = f2bf(v4.y);
            p.z = f2bf(v4.z); p.w = f2bf(v4.w);
            *(ushort4*)&u.b.vs[e][n0] = p;
        }
        __syncthreads();
        #pragma unroll
        for (int ks = 0; ks < 4; ks++) {
            bf16x8 a = *(bf16x8*)&u.b.kr[16 * w + lm][32 * ks + 8 * g];
            #pragma unroll
            for (int eb = 0; eb < 4; eb++) {
                bf16x8 vb = *(bf16x8*)&u.b.vs[16 * eb + lm][32 * ks + 8 * g];
                kvf[eb] = __builtin_amdgcn_mfma_f32_16x16x32_bf16(a, vb, kvf[eb], 0, 0, 0);
            }
        }
    }

    __syncthreads();
    const int bh = b * NHEAD + head;
    float* kvdst = kvp + ((size_t)ns * 256 + bh) * 4096;
    const float s2 = 1.f / 1024.f;
    #pragma unroll
    for (int eb = 0; eb < 4; eb++)
        #pragma unroll
        for (int r = 0; r < 4; r++)
            kvdst[(16 * w + 4 * g + r) * 64 + 16 * eb + lm] = kvf[eb][r] * s2;
    if (tid < HD)
        kmp[((size_t)ns * 256 + bh) * 64 + tid] = skm[tid] * (1.f / 1024.f);
}

// ---------------------------------------------------------------------------
// Phase 2: q = elu(Wq @ x_low + bq)+1 ; z = 1/(q.km+eps) ; rope(q) ;
// out = (qr^T kv)*z + lepe(x).  All GEMMs via MFMA.
// ---------------------------------------------------------------------------
__global__ void __launch_bounds__(256)
phase2_kernel(const float* __restrict__ x, const float* __restrict__ qk_w,
              const float* __restrict__ qk_b,
              const float* __restrict__ lepe_w, const float* __restrict__ lepe_b,
              const float* __restrict__ kvp, const float* __restrict__ kmp,
              float* __restrict__ out, int ns1)
{
    __shared__ union {
        struct { ushort ws[64][40]; ushort xs[128][40]; } a;  // GEMM staging
        struct { ushort qr[128][72]; } bqr;                   // qr^T (bf16, [n][d])
        struct { float  ob[64][132]; } c;                     // out buffer (fp32)
    } u;
    __shared__ ushort kvt[64][72];   // kv^T (bf16, [e][d])
    __shared__ float  kms[64];
    __shared__ float  sz[128];
    __shared__ float  bias_s[64];

    const int tid = threadIdx.x;
    const int w   = tid >> 6;
    const int g   = (tid >> 4) & 3;
    const int lm  = tid & 15;

    const int ns   = blockIdx.x % NSPLIT2;
    const int head = (blockIdx.x / NSPLIT2) % NHEAD;
    const int b    = blockIdx.x / (NSPLIT2 * NHEAD);

    const float* xb = x + (size_t)b * 1024 * NPOS;
    const int wrow  = head * HD;
    const int bh    = b * NHEAD + head;

    // ---- stage kv^T (sum partials, transpose, bf16) + km + bias ----
    #pragma unroll
    for (int i = 0; i < 16; i++) {
        int idx = tid + 256 * i;
        int d = idx >> 6, e = idx & 63;
        float v = 0.f;
        for (int s = 0; s < ns1; s++)
            v += kvp[((size_t)s * 256 + bh) * 4096 + idx];
        kvt[e][d] = f2bf(v);
    }
    if (tid < 64) {
        float v = 0.f;
        for (int s = 0; s < ns1; s++)
            v += kmp[((size_t)s * 256 + bh) * 64 + tid];
        kms[tid] = v;
        bias_s[tid] = qk_b[head * HD + tid];
    }

    float tf[4][2];
    #pragma unroll
    for (int db = 0; db < 4; db++)
        #pragma unroll
        for (int rp = 0; rp < 2; rp++)
            tf[db][rp] = exp2f(-(float)((head * 32 + 8 * db + 2 * g + rp) & 255) * THETA_SCALE);
    const bool htype = (head < 8);

    const int xn = tid & 127, xk = tid >> 7;

    for (int t = 0; t < 2; ++t) {
        const int nbase = ns * 256 + t * NTILE;

        f32x4 acc[4][2];
        #pragma unroll
        for (int db = 0; db < 4; db++)
            #pragma unroll
            for (int nb = 0; nb < 2; nb++) acc[db][nb] = (f32x4){0,0,0,0};

        for (int k0 = 0; k0 < KHALF; k0 += 32) {
            __syncthreads();
            #pragma unroll
            for (int i = 0; i < 2; i++) {
                int idx = tid + 256 * i;
                int d = idx >> 3, kq = (idx & 7) * 4;
                float4 v4 = *(const float4*)&qk_w[(size_t)(wrow + d) * KHALF + k0 + kq];
                ushort4 p; p.x = f2bf(v4.x); p.y = f2bf(v4.y);
                p.z = f2bf(v4.z); p.w = f2bf(v4.w);
                *(ushort4*)&u.a.ws[d][kq] = p;
            }
            {
                const float* xcol = &xb[(size_t)(k0 + 16 * xk) * NPOS + nbase + xn];
                #pragma unroll
                for (int q8 = 0; q8 < 4; q8++) {
                    ushort4 p;
                    p.x = f2bf(xcol[(size_t)(4 * q8 + 0) * NPOS]);
                    p.y = f2bf(xcol[(size_t)(4 * q8 + 1) * NPOS]);
                    p.z = f2bf(xcol[(size_t)(4 * q8 + 2) * NPOS]);
                    p.w = f2bf(xcol[(size_t)(4 * q8 + 3) * NPOS]);
                    *(ushort4*)&u.a.xs[xn][16 * xk + 4 * q8] = p;
                }
            }
            __syncthreads();
            bf16x8 af[4], bfr[2];
            #pragma unroll
            for (int db = 0; db < 4; db++) af[db] = *(bf16x8*)&u.a.ws[16 * db + lm][8 * g];
            #pragma unroll
            for (int nb = 0; nb < 2; nb++) bfr[nb] = *(bf16x8*)&u.a.xs[32 * w + 16 * nb + lm][8 * g];
            #pragma unroll
            for (int db = 0; db < 4; db++)
                #pragma unroll
                for (int nb = 0; nb < 2; nb++)
                    acc[db][nb] = __builtin_amdgcn_mfma_f32_16x16x32_bf16(
                        af[db], bfr[nb], acc[db][nb], 0, 0, 0);
        }

        // ---- bias + elu + 1 ----
        float qv[4][2][4];
        #pragma unroll
        for (int db = 0; db < 4; db++)
            #pragma unroll
            for (int nb = 0; nb < 2; nb++)
                #pragma unroll
                for (int r = 0; r < 4; r++)
                    qv[db][nb][r] = elu1(acc[db][nb][r] + bias_s[16 * db + 4 * g + r]);

        // ---- z denominator per n ----
        float zp[2] = {0.f, 0.f};
        #pragma unroll
        for (int db = 0; db < 4; db++)
            #pragma unroll
            for (int nb = 0; nb < 2; nb++)
                #pragma unroll
                for (int r = 0; r < 4; r++)
                    zp[nb] += qv[db][nb][r] * kms[16 * db + 4 * g + r];
        #pragma unroll
        for (int nb = 0; nb < 2; nb++) {
            zp[nb] += __shfl_xor(zp[nb], 16);
            zp[nb] += __shfl_xor(zp[nb], 32);
        }
        if ((tid & 63) < 16) { sz[32 * w + lm] = zp[0]; sz[32 * w + 16 + lm] = zp[1]; }

        // ---- rope(q) ----
        float qrv[4][2][4];
        #pragma unroll
        for (int db = 0; db < 4; db++)
            #pragma unroll
            for (int nb = 0; nb < 2; nb++) {
                int n = nbase + 32 * w + 16 * nb + lm;
                float pos = htype ? (float)(n >> 5) : (float)(n & 31);
                #pragma unroll
                for (int rp = 0; rp < 2; rp++) {
                    float ang = pos * tf[db][rp];
                    float sn, cs; __sincosf(ang, &sn, &cs);
                    float xr = qv[db][nb][2 * rp], xi = qv[db][nb][2 * rp + 1];
                    qrv[db][nb][2 * rp]     = cs * xr - sn * xi;
                    qrv[db][nb][2 * rp + 1] = sn * xr + cs * xi;
                }
            }

        // ---- stage qr^T [n][d] (b64-packed along r) ----
        __syncthreads();
        #pragma unroll
        for (int db = 0; db < 4; db++)
            #pragma unroll
            for (int nb = 0; nb < 2; nb++) {
                ushort4 p;
                p.x = f2bf(qrv[db][nb][0]); p.y = f2bf(qrv[db][nb][1]);
                p.z = f2bf(qrv[db][nb][2]); p.w = f2bf(qrv[db][nb][3]);
                *(ushort4*)&u.bqr.qr[32 * w + 16 * nb + lm][16 * db + 4 * g] = p;
            }
        __syncthreads();

        // ---- out MFMA: O[e][n] = sum_d kv^T[e][d] * qr[d][n] ----
        f32x4 of[4][2];
        #pragma unroll
        for (int eb = 0; eb < 4; eb++)
            #pragma unroll
            for (int nb = 0; nb < 2; nb++) of[eb][nb] = (f32x4){0,0,0,0};
        #pragma unroll
        for (int ks = 0; ks < 2; ks++) {
            bf16x8 aq[4];
            #pragma unroll
            for (int eb = 0; eb < 4; eb++) aq[eb] = *(bf16x8*)&kvt[16 * eb + lm][32 * ks + 8 * g];
            #pragma unroll
            for (int nb = 0; nb < 2; nb++) {
                bf16x8 bq = *(bf16x8*)&u.bqr.qr[32 * w + 16 * nb + lm][32 * ks + 8 * g];
                #pragma unroll
                for (int eb = 0; eb < 4; eb++)
                    of[eb][nb] = __builtin_amdgcn_mfma_f32_16x16x32_bf16(
                        aq[eb], bq, of[eb][nb], 0, 0, 0);
            }
        }
        __syncthreads();
        #pragma unroll
        for (int eb = 0; eb < 4; eb++)
            #pragma unroll
            for (int nb = 0; nb < 2; nb++)
                #pragma unroll
                for (int r = 0; r < 4; r++)
                    u.c.ob[16 * eb + 4 * g + r][32 * w + 16 * nb + lm] = of[eb][nb][r];
        __syncthreads();

        // ---- epilogue (thread-mapped): z scaling + lepe + store ----
        const int tdx = tid & 31, tdy = tid >> 5;
        const int n0 = nbase + tdx * 4;
        const int h  = n0 >> 5;
        const int w0 = n0 & 31;
        float zq[4];
        #pragma unroll
        for (int j = 0; j < 4; j++) zq[j] = 1.f / (sz[tdx * 4 + j] + 1e-6f);
        #pragma unroll
        for (int r = 0; r < 8; r++) {
            const int c = head * HD + tdy + 8 * r;
            const float* lw = lepe_w + c * 9;
            float lwv[9];
            #pragma unroll
            for (int m = 0; m < 9; m++) lwv[m] = lw[m];
            float lb = lepe_b[c];
            float lac[4] = {lb, lb, lb, lb};
            const float* xc = xb + (size_t)c * NPOS;
            #pragma unroll
            for (int kh = 0; kh < 3; kh++) {
                int hh = h + kh - 1;
                if ((unsigned)hh < 32u) {
                    float tbuf[6];
                    #pragma unroll
                    for (int m = 0; m < 6; m++) {
                        int ww = w0 - 1 + m;
                        tbuf[m] = ((unsigned)ww < 32u) ? xc[hh * 32 + ww] : 0.f;
                    }
                    #pragma unroll
                    for (int j = 0; j < 4; j++)
                        #pragma unroll
                        for (int kw = 0; kw < 3; kw++)
                            lac[j] += tbuf[j + kw] * lwv[kh * 3 + kw];
                }
            }
            float4 o4 = *(float4*)&u.c.ob[tdy + 8 * r][tdx * 4];
            float4 o;
            o.x = o4.x * zq[0] + lac[0];
            o.y = o4.y * zq[1] + lac[1];
            o.z = o4.z * zq[2] + lac[2];
            o.w = o4.w * zq[3] + lac[3];
            *(float4*)&out[(size_t)(b * 1024 + c) * NPOS + n0] = o;
        }
    }
}

// ---------------------------------------------------------------------------
extern "C" void kernel_launch(void* const* d_in, const int* in_sizes, int n_in,
                              void* d_out, int out_size, void* d_ws, size_t ws_size,
                              hipStream_t stream)
{
    const float* x      = (const float*)d_in[0];
    const float* qk_w   = (const float*)d_in[1];
    const float* qk_b   = (const float*)d_in[2];
    const float* lepe_w = (const float*)d_in[3];
    const float* lepe_b = (const float*)d_in[4];
    float* out = (float*)d_out;

    // partial workspace: ns1 * 256 * (4096 + 64) floats
    const size_t need4 = (size_t)4 * 256 * 4160 * sizeof(float);  // 17,039,360
    const int ns1 = (ws_size >= need4) ? 4 : 2;

    float* kvp = (float*)d_ws;
    float* kmp = kvp + (size_t)ns1 * 256 * 4096;

    phase1_kernel<<<dim3(ns1 * B_ * NHEAD), dim3(256), 0, stream>>>(
        x, qk_w, qk_b, kvp, kmp, ns1);
    phase2_kernel<<<dim3(NSPLIT2 * B_ * NHEAD), dim3(256), 0, stream>>>(
        x, qk_w, qk_b, lepe_w, lepe_b, kvp, kmp, out, ns1);
}

// Round 5
// 477.779 us; speedup vs baseline: 3.4782x; 1.4592x over previous
//
#include <hip/hip_runtime.h>

#define B_      16
#define NHEAD   16
#define HD      64
#define NPOS    1024   // 32*32
#define KHALF   512
#define NTILE   128
#define NSPLIT2 4

// log2(10000)/256
#define THETA_SCALE 0.05190512648261504f

typedef __attribute__((ext_vector_type(8))) short bf16x8;   // 8 bf16 = 4 VGPR
typedef __attribute__((ext_vector_type(4))) float f32x4;    // MFMA C/D

__device__ __forceinline__ float elu1(float v) {
    return v > 0.f ? v + 1.f : __expf(v);
}
__device__ __forceinline__ ushort f2bf(float f) {   // fp32 -> bf16 RNE
    unsigned u = __float_as_uint(f);
    return (ushort)((u + 0x7fffu + ((u >> 16) & 1u)) >> 16);
}

// ---------------------------------------------------------------------------
// Phase 1: k = elu(Wk @ x_high + bk)+1 ; rope(k) ; partial kv = kr @ v^T (MFMA),
// partial km.  One block per (b, head, ns).
// ---------------------------------------------------------------------------
__global__ void __launch_bounds__(256)
phase1_kernel(const float* __restrict__ x, const float* __restrict__ qk_w,
              const float* __restrict__ qk_b,
              float* __restrict__ kvp, float* __restrict__ kmp, int ns1)
{
    __shared__ union {
        struct { ushort ws[64][40];  ushort xs[128][40]; } a;   // GEMM staging (bf16)
        struct { ushort kr[64][136]; ushort vs[64][136]; } b;   // kv staging (bf16)
    } u;
    __shared__ float skm[HD];
    __shared__ float bias_s[HD];

    const int tid = threadIdx.x;
    const int w   = tid >> 6;          // wave 0..3
    const int g   = (tid >> 4) & 3;    // 16-lane group within wave
    const int lm  = tid & 15;

    const int ns   = blockIdx.x % ns1;
    const int head = (blockIdx.x / ns1) % NHEAD;
    const int b    = blockIdx.x / (ns1 * NHEAD);

    const float* xb = x + (size_t)b * 1024 * NPOS;
    const int wrow  = 1024 + head * HD;     // k-weight rows in qk_w

    if (tid < HD) { skm[tid] = 0.f; bias_s[tid] = qk_b[1024 + head * HD + tid]; }

    float tf[4][2];
    #pragma unroll
    for (int db = 0; db < 4; db++)
        #pragma unroll
        for (int rp = 0; rp < 2; rp++)
            tf[db][rp] = exp2f(-(float)((head * 32 + 8 * db + 2 * g + rp) & 255) * THETA_SCALE);
    const bool htype = (head < 8);

    f32x4 kvf[4] = {{0,0,0,0},{0,0,0,0},{0,0,0,0},{0,0,0,0}};  // d-block w, eb 0..3

    const int nchunk = NPOS / ns1;
    const int ntiles = nchunk / NTILE;
    const int xn = tid & 127, xk = tid >> 7;   // X staging: column xn, k-half xk

    for (int t = 0; t < ntiles; ++t) {
        const int nbase = ns * nchunk + t * NTILE;

        f32x4 acc[4][2];
        #pragma unroll
        for (int db = 0; db < 4; db++)
            #pragma unroll
            for (int nb = 0; nb < 2; nb++) acc[db][nb] = (f32x4){0,0,0,0};

        for (int k0 = 0; k0 < KHALF; k0 += 32) {
            __syncthreads();
            #pragma unroll
            for (int i = 0; i < 2; i++) {             // W tile 64x32
                int idx = tid + 256 * i;
                int d = idx >> 3, kq = (idx & 7) * 4;
                float4 v4 = *(const float4*)&qk_w[(size_t)(wrow + d) * KHALF + k0 + kq];
                ushort4 p; p.x = f2bf(v4.x); p.y = f2bf(v4.y);
                p.z = f2bf(v4.z); p.w = f2bf(v4.w);
                *(ushort4*)&u.a.ws[d][kq] = p;
            }
            {                                          // X tile 32x128 -> [n][k]
                const float* xcol = &xb[(size_t)(KHALF + k0 + 16 * xk) * NPOS + nbase + xn];
                #pragma unroll
                for (int q8 = 0; q8 < 4; q8++) {
                    ushort4 p;
                    p.x = f2bf(xcol[(size_t)(4 * q8 + 0) * NPOS]);
                    p.y = f2bf(xcol[(size_t)(4 * q8 + 1) * NPOS]);
                    p.z = f2bf(xcol[(size_t)(4 * q8 + 2) * NPOS]);
                    p.w = f2bf(xcol[(size_t)(4 * q8 + 3) * NPOS]);
                    *(ushort4*)&u.a.xs[xn][16 * xk + 4 * q8] = p;
                }
            }
            __syncthreads();
            bf16x8 af[4], bfr[2];
            #pragma unroll
            for (int db = 0; db < 4; db++) af[db] = *(bf16x8*)&u.a.ws[16 * db + lm][8 * g];
            #pragma unroll
            for (int nb = 0; nb < 2; nb++) bfr[nb] = *(bf16x8*)&u.a.xs[32 * w + 16 * nb + lm][8 * g];
            #pragma unroll
            for (int db = 0; db < 4; db++)
                #pragma unroll
                for (int nb = 0; nb < 2; nb++)
                    acc[db][nb] = __builtin_amdgcn_mfma_f32_16x16x32_bf16(
                        af[db], bfr[nb], acc[db][nb], 0, 0, 0);
        }

        float kqv[4][2][4];
        #pragma unroll
        for (int db = 0; db < 4; db++)
            #pragma unroll
            for (int nb = 0; nb < 2; nb++)
                #pragma unroll
                for (int r = 0; r < 4; r++)
                    kqv[db][nb][r] = elu1(acc[db][nb][r] + bias_s[16 * db + 4 * g + r]);

        #pragma unroll
        for (int db = 0; db < 4; db++)
            #pragma unroll
            for (int r = 0; r < 4; r++) {
                float s = kqv[db][0][r] + kqv[db][1][r];
                s += __shfl_xor(s, 1); s += __shfl_xor(s, 2);
                s += __shfl_xor(s, 4); s += __shfl_xor(s, 8);
                if (lm == 0) atomicAdd(&skm[16 * db + 4 * g + r], s);
            }

        float krv[4][2][4];
        #pragma unroll
        for (int db = 0; db < 4; db++)
            #pragma unroll
            for (int nb = 0; nb < 2; nb++) {
                int n = nbase + 32 * w + 16 * nb + lm;
                float pos_h = (float)(n >> 5), pos_w = (float)(n & 31);
                float pos = htype ? pos_h : pos_w;
                #pragma unroll
                for (int rp = 0; rp < 2; rp++) {
                    float ang = pos * tf[db][rp];
                    float sn, cs; __sincosf(ang, &sn, &cs);
                    float xr = kqv[db][nb][2 * rp], xi = kqv[db][nb][2 * rp + 1];
                    krv[db][nb][2 * rp]     = cs * xr - sn * xi;
                    krv[db][nb][2 * rp + 1] = sn * xr + cs * xi;
                }
            }

        __syncthreads();
        #pragma unroll
        for (int db = 0; db < 4; db++)
            #pragma unroll
            for (int nb = 0; nb < 2; nb++)
                #pragma unroll
                for (int r = 0; r < 4; r++)
                    u.b.kr[16 * db + 4 * g + r][32 * w + 16 * nb + lm] = f2bf(krv[db][nb][r]);
        #pragma unroll
        for (int i = 0; i < 8; i++) {
            int idx = tid + 256 * i;
            int e = idx >> 5, n0 = (idx & 31) * 4;
            float4 v4 = *(const float4*)&xb[(size_t)(head * HD + e) * NPOS + nbase + n0];
            ushort4 p; p.x = f2bf(v4.x); p.y = f2bf(v4.y);
            p.z = f2bf(v4.z); p.w = f2bf(v4.w);
            *(ushort4*)&u.b.vs[e][n0] = p;
        }
        __syncthreads();
        #pragma unroll
        for (int ks = 0; ks < 4; ks++) {
            bf16x8 a = *(bf16x8*)&u.b.kr[16 * w + lm][32 * ks + 8 * g];
            #pragma unroll
            for (int eb = 0; eb < 4; eb++) {
                bf16x8 vb = *(bf16x8*)&u.b.vs[16 * eb + lm][32 * ks + 8 * g];
                kvf[eb] = __builtin_amdgcn_mfma_f32_16x16x32_bf16(a, vb, kvf[eb], 0, 0, 0);
            }
        }
    }

    __syncthreads();
    const int bh = b * NHEAD + head;
    float* kvdst = kvp + ((size_t)ns * 256 + bh) * 4096;
    const float s2 = 1.f / 1024.f;
    #pragma unroll
    for (int eb = 0; eb < 4; eb++)
        #pragma unroll
        for (int r = 0; r < 4; r++)
            kvdst[(16 * w + 4 * g + r) * 64 + 16 * eb + lm] = kvf[eb][r] * s2;
    if (tid < HD)
        kmp[((size_t)ns * 256 + bh) * 64 + tid] = skm[tid] * (1.f / 1024.f);
}

// ---------------------------------------------------------------------------
// Phase 2: q = elu(Wq @ x_low + bq)+1 ; z = 1/(q.km+eps) ; rope(q) ;
// out = (qr^T kv)*z + lepe(x).  GEMMs via MFMA; lepe via LDS-staged x-tile.
// ---------------------------------------------------------------------------
__global__ void __launch_bounds__(256)
phase2_kernel(const float* __restrict__ x, const float* __restrict__ qk_w,
              const float* __restrict__ qk_b,
              const float* __restrict__ lepe_w, const float* __restrict__ lepe_b,
              const float* __restrict__ kvp, const float* __restrict__ kmp,
              float* __restrict__ out, int ns1)
{
    __shared__ union {
        struct { ushort ws[64][40]; ushort xs[128][40]; } a;  // GEMM staging
        struct { ushort qr[128][72]; } bqr;                   // qr^T (bf16, [n][d])
        struct { float  ob[64][132]; float lx[32][192]; } c;  // out buf + lepe x-tile
    } u;
    __shared__ ushort kvt[64][72];   // kv^T (bf16, [e][d])
    __shared__ float  kms[64];
    __shared__ float  sz[128];
    __shared__ float  bias_s[64];
    __shared__ float  lws[576];      // lepe weights for this head's 64 channels
    __shared__ float  lbs[64];

    const int tid = threadIdx.x;
    const int w   = tid >> 6;
    const int g   = (tid >> 4) & 3;
    const int lm  = tid & 15;

    const int ns   = blockIdx.x % NSPLIT2;
    const int head = (blockIdx.x / NSPLIT2) % NHEAD;
    const int b    = blockIdx.x / (NSPLIT2 * NHEAD);

    const float* xb = x + (size_t)b * 1024 * NPOS;
    const int wrow  = head * HD;
    const int bh    = b * NHEAD + head;

    // ---- stage kv^T (sum partials, transpose, bf16) + km + bias + lepe wts ----
    #pragma unroll
    for (int i = 0; i < 16; i++) {
        int idx = tid + 256 * i;
        int d = idx >> 6, e = idx & 63;
        float v = 0.f;
        for (int s = 0; s < ns1; s++)
            v += kvp[((size_t)s * 256 + bh) * 4096 + idx];
        kvt[e][d] = f2bf(v);
    }
    if (tid < 64) {
        float v = 0.f;
        for (int s = 0; s < ns1; s++)
            v += kmp[((size_t)s * 256 + bh) * 64 + tid];
        kms[tid] = v;
        bias_s[tid] = qk_b[head * HD + tid];
        lbs[tid]    = lepe_b[head * HD + tid];
    }
    for (int i = tid; i < 576; i += 256)
        lws[i] = lepe_w[(size_t)(head * HD) * 9 + i];

    float tf[4][2];
    #pragma unroll
    for (int db = 0; db < 4; db++)
        #pragma unroll
        for (int rp = 0; rp < 2; rp++)
            tf[db][rp] = exp2f(-(float)((head * 32 + 8 * db + 2 * g + rp) & 255) * THETA_SCALE);
    const bool htype = (head < 8);

    const int xn = tid & 127, xk = tid >> 7;

    for (int t = 0; t < 2; ++t) {
        const int nbase = ns * 256 + t * NTILE;

        f32x4 acc[4][2];
        #pragma unroll
        for (int db = 0; db < 4; db++)
            #pragma unroll
            for (int nb = 0; nb < 2; nb++) acc[db][nb] = (f32x4){0,0,0,0};

        for (int k0 = 0; k0 < KHALF; k0 += 32) {
            __syncthreads();
            #pragma unroll
            for (int i = 0; i < 2; i++) {
                int idx = tid + 256 * i;
                int d = idx >> 3, kq = (idx & 7) * 4;
                float4 v4 = *(const float4*)&qk_w[(size_t)(wrow + d) * KHALF + k0 + kq];
                ushort4 p; p.x = f2bf(v4.x); p.y = f2bf(v4.y);
                p.z = f2bf(v4.z); p.w = f2bf(v4.w);
                *(ushort4*)&u.a.ws[d][kq] = p;
            }
            {
                const float* xcol = &xb[(size_t)(k0 + 16 * xk) * NPOS + nbase + xn];
                #pragma unroll
                for (int q8 = 0; q8 < 4; q8++) {
                    ushort4 p;
                    p.x = f2bf(xcol[(size_t)(4 * q8 + 0) * NPOS]);
                    p.y = f2bf(xcol[(size_t)(4 * q8 + 1) * NPOS]);
                    p.z = f2bf(xcol[(size_t)(4 * q8 + 2) * NPOS]);
                    p.w = f2bf(xcol[(size_t)(4 * q8 + 3) * NPOS]);
                    *(ushort4*)&u.a.xs[xn][16 * xk + 4 * q8] = p;
                }
            }
            __syncthreads();
            bf16x8 af[4], bfr[2];
            #pragma unroll
            for (int db = 0; db < 4; db++) af[db] = *(bf16x8*)&u.a.ws[16 * db + lm][8 * g];
            #pragma unroll
            for (int nb = 0; nb < 2; nb++) bfr[nb] = *(bf16x8*)&u.a.xs[32 * w + 16 * nb + lm][8 * g];
            #pragma unroll
            for (int db = 0; db < 4; db++)
                #pragma unroll
                for (int nb = 0; nb < 2; nb++)
                    acc[db][nb] = __builtin_amdgcn_mfma_f32_16x16x32_bf16(
                        af[db], bfr[nb], acc[db][nb], 0, 0, 0);
        }

        // ---- bias + elu + 1 ----
        float qv[4][2][4];
        #pragma unroll
        for (int db = 0; db < 4; db++)
            #pragma unroll
            for (int nb = 0; nb < 2; nb++)
                #pragma unroll
                for (int r = 0; r < 4; r++)
                    qv[db][nb][r] = elu1(acc[db][nb][r] + bias_s[16 * db + 4 * g + r]);

        // ---- z denominator per n ----
        float zp[2] = {0.f, 0.f};
        #pragma unroll
        for (int db = 0; db < 4; db++)
            #pragma unroll
            for (int nb = 0; nb < 2; nb++)
                #pragma unroll
                for (int r = 0; r < 4; r++)
                    zp[nb] += qv[db][nb][r] * kms[16 * db + 4 * g + r];
        #pragma unroll
        for (int nb = 0; nb < 2; nb++) {
            zp[nb] += __shfl_xor(zp[nb], 16);
            zp[nb] += __shfl_xor(zp[nb], 32);
        }
        if ((tid & 63) < 16) { sz[32 * w + lm] = zp[0]; sz[32 * w + 16 + lm] = zp[1]; }

        // ---- rope(q) ----
        float qrv[4][2][4];
        #pragma unroll
        for (int db = 0; db < 4; db++)
            #pragma unroll
            for (int nb = 0; nb < 2; nb++) {
                int n = nbase + 32 * w + 16 * nb + lm;
                float pos = htype ? (float)(n >> 5) : (float)(n & 31);
                #pragma unroll
                for (int rp = 0; rp < 2; rp++) {
                    float ang = pos * tf[db][rp];
                    float sn, cs; __sincosf(ang, &sn, &cs);
                    float xr = qv[db][nb][2 * rp], xi = qv[db][nb][2 * rp + 1];
                    qrv[db][nb][2 * rp]     = cs * xr - sn * xi;
                    qrv[db][nb][2 * rp + 1] = sn * xr + cs * xi;
                }
            }

        // ---- stage qr^T [n][d] ----
        __syncthreads();
        #pragma unroll
        for (int db = 0; db < 4; db++)
            #pragma unroll
            for (int nb = 0; nb < 2; nb++) {
                ushort4 p;
                p.x = f2bf(qrv[db][nb][0]); p.y = f2bf(qrv[db][nb][1]);
                p.z = f2bf(qrv[db][nb][2]); p.w = f2bf(qrv[db][nb][3]);
                *(ushort4*)&u.bqr.qr[32 * w + 16 * nb + lm][16 * db + 4 * g] = p;
            }
        __syncthreads();

        // ---- out MFMA: O[e][n] = sum_d kv^T[e][d] * qr[d][n] ----
        f32x4 of[4][2];
        #pragma unroll
        for (int eb = 0; eb < 4; eb++)
            #pragma unroll
            for (int nb = 0; nb < 2; nb++) of[eb][nb] = (f32x4){0,0,0,0};
        #pragma unroll
        for (int ks = 0; ks < 2; ks++) {
            bf16x8 aq[4];
            #pragma unroll
            for (int eb = 0; eb < 4; eb++) aq[eb] = *(bf16x8*)&kvt[16 * eb + lm][32 * ks + 8 * g];
            #pragma unroll
            for (int nb = 0; nb < 2; nb++) {
                bf16x8 bq = *(bf16x8*)&u.bqr.qr[32 * w + 16 * nb + lm][32 * ks + 8 * g];
                #pragma unroll
                for (int eb = 0; eb < 4; eb++)
                    of[eb][nb] = __builtin_amdgcn_mfma_f32_16x16x32_bf16(
                        aq[eb], bq, of[eb][nb], 0, 0, 0);
            }
        }
        __syncthreads();
        #pragma unroll
        for (int eb = 0; eb < 4; eb++)
            #pragma unroll
            for (int nb = 0; nb < 2; nb++)
                #pragma unroll
                for (int r = 0; r < 4; r++)
                    u.c.ob[16 * eb + 4 * g + r][32 * w + 16 * nb + lm] = of[eb][nb][r];
        __syncthreads();

        // ---- epilogue: z-scale + lepe (LDS-staged x) + store ----
        const int tdx = tid & 31, tdy = tid >> 5;
        const int n0 = nbase + tdx * 4;
        const int h  = n0 >> 5;
        const int w0 = n0 & 31;
        const int h0 = nbase >> 5;
        float zq[4];
        #pragma unroll
        for (int j = 0; j < 4; j++) zq[j] = 1.f / (sz[tdx * 4 + j] + 1e-6f);

        #pragma unroll
        for (int hf = 0; hf < 2; ++hf) {
            // cooperative load: 32 channels x 6 rows (halo, zero-padded) x 32 cols
            #pragma unroll
            for (int j = 0; j < 6; j++) {
                int idx = tid + 256 * j;
                int c   = idx / 48;
                int rem = idx % 48;
                int row = rem >> 3, f4 = rem & 7;
                int hh  = h0 - 1 + row;
                float4 v4 = make_float4(0.f, 0.f, 0.f, 0.f);
                if ((unsigned)hh < 32u)
                    v4 = *(const float4*)&xb[(size_t)(head * HD + hf * 32 + c) * NPOS
                                             + hh * 32 + 4 * f4];
                *(float4*)&u.c.lx[c][row * 32 + 4 * f4] = v4;
            }
            __syncthreads();
            #pragma unroll
            for (int rq = 0; rq < 4; rq++) {
                const int rr = hf * 4 + rq;
                const int cl = tdy + 8 * rr - hf * 32;     // 0..31 within half
                const int c  = head * HD + tdy + 8 * rr;   // global channel
                const float* lwv = &lws[(tdy + 8 * rr) * 9];
                float lb = lbs[tdy + 8 * rr];
                float lac[4] = {lb, lb, lb, lb};
                #pragma unroll
                for (int kh = 0; kh < 3; kh++) {
                    const float* lrow = &u.c.lx[cl][(h - h0 + kh) * 32];
                    float tbuf[6];
                    #pragma unroll
                    for (int m = 0; m < 6; m++) {
                        int ww = w0 - 1 + m;
                        tbuf[m] = ((unsigned)ww < 32u) ? lrow[ww] : 0.f;
                    }
                    #pragma unroll
                    for (int j = 0; j < 4; j++)
                        #pragma unroll
                        for (int kw = 0; kw < 3; kw++)
                            lac[j] += tbuf[j + kw] * lwv[kh * 3 + kw];
                }
                float4 o4 = *(float4*)&u.c.ob[tdy + 8 * rr][tdx * 4];
                float4 o;
                o.x = o4.x * zq[0] + lac[0];
                o.y = o4.y * zq[1] + lac[1];
                o.z = o4.z * zq[2] + lac[2];
                o.w = o4.w * zq[3] + lac[3];
                *(float4*)&out[(size_t)(b * 1024 + c) * NPOS + n0] = o;
            }
            __syncthreads();   // protect lx reuse (hf=1) and union reuse (next t)
        }
    }
}

// ---------------------------------------------------------------------------
extern "C" void kernel_launch(void* const* d_in, const int* in_sizes, int n_in,
                              void* d_out, int out_size, void* d_ws, size_t ws_size,
                              hipStream_t stream)
{
    const float* x      = (const float*)d_in[0];
    const float* qk_w   = (const float*)d_in[1];
    const float* qk_b   = (const float*)d_in[2];
    const float* lepe_w = (const float*)d_in[3];
    const float* lepe_b = (const float*)d_in[4];
    float* out = (float*)d_out;

    // partial workspace: ns1 * 256 * (4096 + 64) floats
    const size_t need4 = (size_t)4 * 256 * 4160 * sizeof(float);  // 17,039,360
    const int ns1 = (ws_size >= need4) ? 4 : 2;

    float* kvp = (float*)d_ws;
    float* kmp = kvp + (size_t)ns1 * 256 * 4096;

    phase1_kernel<<<dim3(ns1 * B_ * NHEAD), dim3(256), 0, stream>>>(
        x, qk_w, qk_b, kvp, kmp, ns1);
    phase2_kernel<<<dim3(NSPLIT2 * B_ * NHEAD), dim3(256), 0, stream>>>(
        x, qk_w, qk_b, lepe_w, lepe_b, kvp, kmp, out, ns1);
}